// Round 5
// baseline (2347.344 us; speedup 1.0000x reference)
//
#include <hip/hip_runtime.h>

#define NROWS 65536
#define SB 256  // stride of the main ws activation buffer

__device__ __forceinline__ float frelu(float v) { return fmaxf(v, 0.f); }

// ---------------- ws layout (floats, relative to weight region W) ----------------
// W = ws + NROWS*SB
#define OFF_WT1   0        // [168][128]  enc_w1^T
#define OFF_WT2   21504    // [128][256]  enc_w2^T
#define OFF_WT3   54272    // [256][256]  enc_w3^T
#define OFF_WTQ   119808   // [256][64]   q_w^T
#define OFF_WTD1  136192   // [64][256]   dec_w1^T
#define OFF_WTD2  152576   // [256][128]  dec_w2^T
#define OFF_WTD3  185344   // [128][256]  dec_w3^T (o>=165 zero-padded)
#define OFF_WAPE  218112   // [2][64][32][4] enc_res_wa packed
#define OFF_WBTE  234496   // [2][32][256]   enc_res_wb^T
#define OFF_WAPD  250880   // [2][64][32][4] dec_res_wa packed
#define OFF_WBTD  267264   // [2][32][256]   dec_res_wb^T
#define OFF_ETG   283648   // [4][512][64]  codebook row-major
#define OFF_EN2   414720   // [4][512]      ||e_k||^2
#define OFF_DSUM  416768   // [1]
#define PREP_N    416769

// ---------------- fused prep kernel: all weight transposes + codebook tables ----
__global__ void prep_k(const float* __restrict__ ew1, const float* __restrict__ ew2,
                       const float* __restrict__ ew3, const float* __restrict__ qw,
                       const float* __restrict__ dw1, const float* __restrict__ dw2,
                       const float* __restrict__ dw3, const float* __restrict__ ewa,
                       const float* __restrict__ ewb, const float* __restrict__ dwa,
                       const float* __restrict__ dwb, const float* __restrict__ embeds,
                       float* __restrict__ W) {
  int idx = blockIdx.x * 256 + threadIdx.x;
  if (idx < 21504) {  // wT1 [168][128] <- ew1 [128][165]
    int k = idx >> 7, o = idx & 127;
    W[OFF_WT1 + idx] = (k < 165) ? ew1[o * 165 + k] : 0.f;
    return;
  }
  idx -= 21504;
  if (idx < 32768) {  // wT2 [128][256] <- ew2 [256][128]
    int k = idx >> 8, o = idx & 255;
    W[OFF_WT2 + idx] = ew2[o * 128 + k];
    return;
  }
  idx -= 32768;
  if (idx < 65536) {  // wT3 [256][256] <- ew3 [256][256]
    int k = idx >> 8, o = idx & 255;
    W[OFF_WT3 + idx] = ew3[o * 256 + k];
    return;
  }
  idx -= 65536;
  if (idx < 16384) {  // wTq [256][64] <- qw [64][256]
    int k = idx >> 6, o = idx & 63;
    W[OFF_WTQ + idx] = qw[o * 256 + k];
    return;
  }
  idx -= 16384;
  if (idx < 16384) {  // wTd1 [64][256] <- dw1 [256][64]
    int k = idx >> 8, o = idx & 255;
    W[OFF_WTD1 + idx] = dw1[o * 64 + k];
    return;
  }
  idx -= 16384;
  if (idx < 32768) {  // wTd2 [256][128] <- dw2 [128][256]
    int k = idx >> 7, o = idx & 127;
    W[OFF_WTD2 + idx] = dw2[o * 256 + k];
    return;
  }
  idx -= 32768;
  if (idx < 32768) {  // wTd3 [128][256] <- dw3 [165][128], pad o>=165
    int k = idx >> 8, o = idx & 255;
    W[OFF_WTD3 + idx] = (o < 165) ? dw3[o * 128 + k] : 0.f;
    return;
  }
  idx -= 32768;
  if (idx < 16384) {  // waPe [2][64][32][4] <- ewa [2][32][256]
    int l = idx >> 13, rem = idx & 8191;
    int k4 = rem >> 7, rem2 = rem & 127, o = rem2 >> 2, kk = rem2 & 3;
    W[OFF_WAPE + idx] = ewa[l * 8192 + o * 256 + k4 * 4 + kk];
    return;
  }
  idx -= 16384;
  if (idx < 16384) {  // wbTe [2][32][256] <- ewb [2][256][32]
    int l = idx >> 13, rem = idx & 8191;
    int k = rem >> 8, o = rem & 255;
    W[OFF_WBTE + idx] = ewb[l * 8192 + o * 32 + k];
    return;
  }
  idx -= 16384;
  if (idx < 16384) {  // waPd
    int l = idx >> 13, rem = idx & 8191;
    int k4 = rem >> 7, rem2 = rem & 127, o = rem2 >> 2, kk = rem2 & 3;
    W[OFF_WAPD + idx] = dwa[l * 8192 + o * 256 + k4 * 4 + kk];
    return;
  }
  idx -= 16384;
  if (idx < 16384) {  // wbTd
    int l = idx >> 13, rem = idx & 8191;
    int k = rem >> 8, o = rem & 255;
    W[OFF_WBTD + idx] = dwb[l * 8192 + o * 32 + k];
    return;
  }
  idx -= 16384;
  if (idx < 131072) {  // etg[l][k][d] = embeds[l][d][k]
    int d = idx & 63, k = (idx >> 6) & 511, l = idx >> 15;
    W[OFF_ETG + idx] = embeds[(l * 64 + d) * 512 + k];
    return;
  }
  idx -= 131072;
  if (idx < 2048) {  // en2
    int l = idx >> 9, k = idx & 511;
    float s = 0.f;
    for (int d = 0; d < 64; ++d) {
      float e = embeds[(l * 64 + d) * 512 + k];
      s = fmaf(e, e, s);
    }
    W[OFF_EN2 + idx] = s;
    return;
  }
  idx -= 2048;
  if (idx == 0) W[OFF_DSUM] = 0.f;
}

// ---------------- 1x1-conv, transposed weights, coalesced everything ----------------
// 32 rows/block, 256 threads (4 waves, 8 rows/wave). Lane owns CP consecutive
// outputs o = lane*CP+j; weight loads wT[k][lane*CP] are fully coalesced
// dwordx{CP}; x comes from LDS wave-uniform broadcast; stores are vector &
// coalesced. One barrier total. Safe in-place (reads precede writes per row).
template <int CIN, int CINP, int COUT, int CP, int INSTRIDE, int OUTSTRIDE, bool RELU_IN,
          bool RELU_OUT>
__global__ __launch_bounds__(256, 4) void conv2_k(const float* in, const float* __restrict__ wT,
                                                  const float* __restrict__ b, float* out) {
  constexpr int COUTP = 64 * CP;
  constexpr bool GUARD = (COUT != COUTP);
  typedef float vCP __attribute__((ext_vector_type(CP)));
  __shared__ float xs[32][CINP];
  const int tid = threadIdx.x, lane = tid & 63, wv = tid >> 6;
  const long row0 = (long)blockIdx.x * 32;

  for (int i = tid; i < 32 * CINP; i += 256) {
    const int r = i / CINP, c = i % CINP;
    float v = (CIN == CINP || c < CIN) ? in[(row0 + r) * (long)INSTRIDE + c] : 0.f;
    if (RELU_IN) v = frelu(v);
    xs[r][c] = v;
  }
  __syncthreads();

  float acc[8][CP];
#pragma unroll
  for (int i = 0; i < 8; ++i)
#pragma unroll
    for (int j = 0; j < CP; ++j) acc[i][j] = 0.f;

  const float* wbase = wT + lane * CP;
#pragma unroll 4
  for (int k0 = 0; k0 < CINP; k0 += 4) {
    vCP wk[4];
#pragma unroll
    for (int kk = 0; kk < 4; ++kk) wk[kk] = *(const vCP*)(wbase + (k0 + kk) * COUTP);
#pragma unroll
    for (int rj = 0; rj < 8; ++rj) {
      const float4 x = *(const float4*)(&xs[wv * 8 + rj][k0]);
#pragma unroll
      for (int j = 0; j < CP; ++j) {
        acc[rj][j] = fmaf(x.x, wk[0][j], acc[rj][j]);
        acc[rj][j] = fmaf(x.y, wk[1][j], acc[rj][j]);
        acc[rj][j] = fmaf(x.z, wk[2][j], acc[rj][j]);
        acc[rj][j] = fmaf(x.w, wk[3][j], acc[rj][j]);
      }
    }
  }

  float bias[CP];
#pragma unroll
  for (int j = 0; j < CP; ++j) {
    const int o = lane * CP + j;
    bias[j] = (!GUARD || o < COUT) ? b[o] : 0.f;
  }
#pragma unroll
  for (int rj = 0; rj < 8; ++rj) {
    const long rbase = (row0 + wv * 8 + rj) * (long)OUTSTRIDE;
    if constexpr (!GUARD) {
      vCP v;
#pragma unroll
      for (int j = 0; j < CP; ++j) {
        const float t = acc[rj][j] + bias[j];
        v[j] = RELU_OUT ? frelu(t) : t;
      }
      *(vCP*)(out + rbase + lane * CP) = v;
    } else {
#pragma unroll
      for (int j = 0; j < CP; ++j) {
        const int o = lane * CP + j;
        if (o < COUT) {
          const float t = acc[rj][j] + bias[j];
          out[rbase + o] = RELU_OUT ? frelu(t) : t;
        }
      }
    }
  }
}

// ---------------- fused ResBlock PAIR (two resblocks, one kernel) ----------------
// 32 rows/block; rows & ts are strictly wave-private after staging, so the
// whole 2-resblock chain runs with ONE barrier. waP [2][64][32][4], wbT [2][32][256].
// Phase B uses NAMED float4 wk0..wk3 with explicit .x/.y/.z/.w — round 4's
// (&wk[0].x)[j] address-of-member indexing forced wk[] to scratch (2.3 GB/dispatch
// of spill traffic). All register arrays now have compile-time-constant indices.
__global__ __launch_bounds__(256, 4) void resblock_pair_k(
    const float* in, const float* __restrict__ waP, const float* __restrict__ ba,
    const float* __restrict__ wbT, const float* __restrict__ bb, float* out) {
  __shared__ float xs[32][256];
  __shared__ float ts[32][36];
  const int tid = threadIdx.x, lane = tid & 63, wv = tid >> 6;
  const long row0 = (long)blockIdx.x * 32;

  for (int i = tid; i < 32 * 256; i += 256) {
    const int r = i >> 8, c = i & 255;
    xs[r][c] = in[(row0 + r) * (long)SB + c];
  }
  __syncthreads();

  const int o32 = lane & 31;
  const int rh = lane >> 5;

  for (int li = 0; li < 2; ++li) {
    const float* waPl = waP + li * 8192;
    const float* wbl = wbT + li * 8192;
    const float bal = ba[li * 32 + o32];

    // phase A: t = relu(wa . relu(x) + ba); lane half rh handles 4 rows, o32 output
    float accA[4] = {0.f, 0.f, 0.f, 0.f};
#pragma unroll 4
    for (int k0 = 0; k0 < 256; k0 += 4) {
      const float4 wq = *(const float4*)(waPl + k0 * 32 + o32 * 4);
#pragma unroll
      for (int rr = 0; rr < 4; ++rr) {
        const float4 x = *(const float4*)(&xs[wv * 8 + rh * 4 + rr][k0]);
        accA[rr] = fmaf(frelu(x.x), wq.x, accA[rr]);
        accA[rr] = fmaf(frelu(x.y), wq.y, accA[rr]);
        accA[rr] = fmaf(frelu(x.z), wq.z, accA[rr]);
        accA[rr] = fmaf(frelu(x.w), wq.w, accA[rr]);
      }
    }
#pragma unroll
    for (int rr = 0; rr < 4; ++rr)
      ts[wv * 8 + rh * 4 + rr][o32] = frelu(accA[rr] + bal);

    // phase B: x += wb . t + bb (wave-local; no barrier needed)
    float acc2[8][4];
#pragma unroll
    for (int i = 0; i < 8; ++i)
#pragma unroll
      for (int j = 0; j < 4; ++j) acc2[i][j] = 0.f;

#pragma unroll
    for (int k0 = 0; k0 < 32; k0 += 4) {
      const float4 wk0 = *(const float4*)(wbl + (k0 + 0) * 256 + lane * 4);
      const float4 wk1 = *(const float4*)(wbl + (k0 + 1) * 256 + lane * 4);
      const float4 wk2 = *(const float4*)(wbl + (k0 + 2) * 256 + lane * 4);
      const float4 wk3 = *(const float4*)(wbl + (k0 + 3) * 256 + lane * 4);
#pragma unroll
      for (int rj = 0; rj < 8; ++rj) {
        const float4 t4 = *(const float4*)(&ts[wv * 8 + rj][k0]);
        acc2[rj][0] = fmaf(t4.x, wk0.x, acc2[rj][0]);
        acc2[rj][1] = fmaf(t4.x, wk0.y, acc2[rj][1]);
        acc2[rj][2] = fmaf(t4.x, wk0.z, acc2[rj][2]);
        acc2[rj][3] = fmaf(t4.x, wk0.w, acc2[rj][3]);
        acc2[rj][0] = fmaf(t4.y, wk1.x, acc2[rj][0]);
        acc2[rj][1] = fmaf(t4.y, wk1.y, acc2[rj][1]);
        acc2[rj][2] = fmaf(t4.y, wk1.z, acc2[rj][2]);
        acc2[rj][3] = fmaf(t4.y, wk1.w, acc2[rj][3]);
        acc2[rj][0] = fmaf(t4.z, wk2.x, acc2[rj][0]);
        acc2[rj][1] = fmaf(t4.z, wk2.y, acc2[rj][1]);
        acc2[rj][2] = fmaf(t4.z, wk2.z, acc2[rj][2]);
        acc2[rj][3] = fmaf(t4.z, wk2.w, acc2[rj][3]);
        acc2[rj][0] = fmaf(t4.w, wk3.x, acc2[rj][0]);
        acc2[rj][1] = fmaf(t4.w, wk3.y, acc2[rj][1]);
        acc2[rj][2] = fmaf(t4.w, wk3.z, acc2[rj][2]);
        acc2[rj][3] = fmaf(t4.w, wk3.w, acc2[rj][3]);
      }
    }
    const float4 bbv = *(const float4*)(bb + li * 256 + lane * 4);
#pragma unroll
    for (int rj = 0; rj < 8; ++rj) {
      const int r = wv * 8 + rj;
      const float4 xv = *(const float4*)(&xs[r][lane * 4]);
      float4 nv;
      nv.x = xv.x + acc2[rj][0] + bbv.x;
      nv.y = xv.y + acc2[rj][1] + bbv.y;
      nv.z = xv.z + acc2[rj][2] + bbv.z;
      nv.w = xv.w + acc2[rj][3] + bbv.w;
      if (li == 0)
        *(float4*)(&xs[r][lane * 4]) = nv;
      else
        *(float4*)(out + (row0 + r) * (long)SB + lane * 4) = nv;
    }
  }
}

// ---------------- residual VQ (4 levels, exact fp32 argmin) ----------------
// Barrier-free, coalesced codebook reads from global ([l][d][k] layout,
// lane-consecutive float4, L2-resident). score = en2[k] - 2*res.e_k.
// First-min tie-break identical to jnp.argmin.
__global__ __launch_bounds__(256, 4) void vq_k(float* buf, const float* __restrict__ embeds,
                                               const float* __restrict__ en2,
                                               const float* __restrict__ etg,
                                               float* __restrict__ dsum) {
  __shared__ float resL[32][68];
  const int tid = threadIdx.x;
  const int lane = tid & 63;
  const int wv = tid >> 6;
  const long row0 = (long)blockIdx.x * 32;

  for (int rj = 0; rj < 8; ++rj) {
    const int r = wv * 8 + rj;
    resL[r][lane] = buf[(row0 + r) * (long)SB + lane];
  }

  float dloc = 0.f;

  for (int l = 0; l < 4; ++l) {
    float best[8];
    int bk[8];
#pragma unroll
    for (int i = 0; i < 8; ++i) {
      best[i] = 3.4e38f;
      bk[i] = 0;
    }

    for (int kc = 0; kc < 2; ++kc) {
      float acc[8][4];
#pragma unroll
      for (int i = 0; i < 8; ++i)
#pragma unroll
        for (int j = 0; j < 4; ++j) acc[i][j] = 0.f;

      const float* eb = embeds + ((long)l << 15) + (kc << 8) + lane * 4;
#pragma unroll 2
      for (int dq = 0; dq < 16; ++dq) {
        float4 x4[8];
#pragma unroll
        for (int rj = 0; rj < 8; ++rj) x4[rj] = *(const float4*)(&resL[wv * 8 + rj][dq * 4]);
#pragma unroll
        for (int dd = 0; dd < 4; ++dd) {
          const float4 e4 = *(const float4*)(eb + ((dq * 4 + dd) << 9));
#pragma unroll
          for (int rj = 0; rj < 8; ++rj) {
            const float xv = dd == 0 ? x4[rj].x : dd == 1 ? x4[rj].y : dd == 2 ? x4[rj].z : x4[rj].w;
            acc[rj][0] = fmaf(xv, e4.x, acc[rj][0]);
            acc[rj][1] = fmaf(xv, e4.y, acc[rj][1]);
            acc[rj][2] = fmaf(xv, e4.z, acc[rj][2]);
            acc[rj][3] = fmaf(xv, e4.w, acc[rj][3]);
          }
        }
      }

      const float4 e2 = *(const float4*)(en2 + l * 512 + kc * 256 + lane * 4);
#pragma unroll
      for (int rj = 0; rj < 8; ++rj) {
#pragma unroll
        for (int j = 0; j < 4; ++j) {
          const float ev = j == 0 ? e2.x : j == 1 ? e2.y : j == 2 ? e2.z : e2.w;
          const float s = fmaf(-2.f, acc[rj][j], ev);
          const int k = kc * 256 + lane * 4 + j;
          if (s < best[rj]) {
            best[rj] = s;
            bk[rj] = k;
          }
        }
      }
    }

    // cross-lane first-min argmin
#pragma unroll
    for (int rj = 0; rj < 8; ++rj) {
      float bv = best[rj];
      int bi = bk[rj];
#pragma unroll
      for (int m = 1; m < 64; m <<= 1) {
        const float ov = __shfl_xor(bv, m, 64);
        const int ok = __shfl_xor(bi, m, 64);
        if (ov < bv || (ov == bv && ok < bi)) {
          bv = ov;
          bi = ok;
        }
      }
      bk[rj] = bi;
    }

    // gather + straight-through update
#pragma unroll
    for (int rj = 0; rj < 8; ++rj) {
      const int r = wv * 8 + rj;
      const float q = etg[((long)((l << 9) + bk[rj])) * 64 + lane];
      const float res = resL[r][lane];
      const float t = q - res;
      const float qst = res + t;
      dloc = fmaf(t, t, dloc);
      resL[r][lane] = res - qst;
      if (l == 0) buf[(row0 + r) * (long)SB + lane] = qst;
    }
  }

#pragma unroll
  for (int m = 1; m < 64; m <<= 1) dloc += __shfl_xor(dloc, m, 64);
  if (lane == 0) atomicAdd(dsum, dloc);
}

__global__ void finalize_k(const float* __restrict__ dsum, float* __restrict__ out) {
  if (threadIdx.x == 0 && blockIdx.x == 0)
    out[0] = *dsum * (1.0f / (4.0f * 65536.0f * 64.0f));
}

// ---------------- launch ----------------
extern "C" void kernel_launch(void* const* d_in, const int* in_sizes, int n_in, void* d_out,
                              int out_size, void* d_ws, size_t ws_size, hipStream_t stream) {
  (void)in_sizes; (void)n_in; (void)out_size; (void)ws_size;
  const float* x = (const float*)d_in[0];
  const float* enc_w1 = (const float*)d_in[1];
  const float* enc_b1 = (const float*)d_in[2];
  const float* enc_w2 = (const float*)d_in[3];
  const float* enc_b2 = (const float*)d_in[4];
  const float* enc_w3 = (const float*)d_in[5];
  const float* enc_b3 = (const float*)d_in[6];
  const float* enc_res_wa = (const float*)d_in[7];
  const float* enc_res_ba = (const float*)d_in[8];
  const float* enc_res_wb = (const float*)d_in[9];
  const float* enc_res_bb = (const float*)d_in[10];
  const float* q_w = (const float*)d_in[11];
  const float* q_b = (const float*)d_in[12];
  const float* embeds = (const float*)d_in[13];
  const float* dec_w1 = (const float*)d_in[14];
  const float* dec_b1 = (const float*)d_in[15];
  const float* dec_res_wa = (const float*)d_in[16];
  const float* dec_res_ba = (const float*)d_in[17];
  const float* dec_res_wb = (const float*)d_in[18];
  const float* dec_res_bb = (const float*)d_in[19];
  const float* dec_w2 = (const float*)d_in[20];
  const float* dec_b2 = (const float*)d_in[21];
  const float* dec_w3 = (const float*)d_in[22];
  const float* dec_b3 = (const float*)d_in[23];

  float* ws = (float*)d_ws;
  float* buf = ws;                          // [N][256]
  float* W = ws + (long)NROWS * SB;         // weight/codebook region

  float* dout = (float*)d_out;

  prep_k<<<(PREP_N + 255) / 256, 256, 0, stream>>>(enc_w1, enc_w2, enc_w3, q_w, dec_w1, dec_w2,
                                                   dec_w3, enc_res_wa, enc_res_wb, dec_res_wa,
                                                   dec_res_wb, embeds, W);

  const int GB = NROWS / 32;  // 2048 blocks

  // encoder
  conv2_k<165, 168, 128, 2, 165, SB, false, true><<<GB, 256, 0, stream>>>(x, W + OFF_WT1, enc_b1, buf);
  conv2_k<128, 128, 256, 4, SB, SB, false, true><<<GB, 256, 0, stream>>>(buf, W + OFF_WT2, enc_b2, buf);
  conv2_k<256, 256, 256, 4, SB, SB, false, false><<<GB, 256, 0, stream>>>(buf, W + OFF_WT3, enc_b3, buf);
  resblock_pair_k<<<GB, 256, 0, stream>>>(buf, W + OFF_WAPE, enc_res_ba, W + OFF_WBTE, enc_res_bb, buf);
  conv2_k<256, 256, 64, 1, SB, SB, true, false><<<GB, 256, 0, stream>>>(buf, W + OFF_WTQ, q_b, buf);

  // residual VQ
  vq_k<<<GB, 256, 0, stream>>>(buf, embeds, W + OFF_EN2, W + OFF_ETG, W + OFF_DSUM);

  // decoder
  conv2_k<64, 64, 256, 4, SB, SB, false, false><<<GB, 256, 0, stream>>>(buf, W + OFF_WTD1, dec_b1, buf);
  resblock_pair_k<<<GB, 256, 0, stream>>>(buf, W + OFF_WAPD, dec_res_ba, W + OFF_WBTD, dec_res_bb, buf);
  conv2_k<256, 256, 128, 2, SB, SB, true, true><<<GB, 256, 0, stream>>>(buf, W + OFF_WTD2, dec_b2, buf);
  conv2_k<128, 128, 165, 4, SB, 165, false, false><<<GB, 256, 0, stream>>>(buf, W + OFF_WTD3, dec_b3, dout);

  finalize_k<<<1, 64, 0, stream>>>(W + OFF_DSUM, dout + (long)NROWS * 165);
}

// Round 6
// 1234.043 us; speedup vs baseline: 1.9022x; 1.9022x over previous
//
#include <hip/hip_runtime.h>

#define NROWS 65536
#define SB 256  // stride of the main ws activation buffer

__device__ __forceinline__ float frelu(float v) { return fmaxf(v, 0.f); }

// ---------------- ws layout (floats, relative to weight region W) ----------------
// W = ws + NROWS*SB
#define OFF_WT1   0        // [168][128]  enc_w1^T
#define OFF_WT2   21504    // [128][256]  enc_w2^T
#define OFF_WT3   54272    // [256][256]  enc_w3^T
#define OFF_WTQ   119808   // [256][64]   q_w^T
#define OFF_WTD1  136192   // [64][256]   dec_w1^T
#define OFF_WTD2  152576   // [256][128]  dec_w2^T
#define OFF_WTD3  185344   // [128][256]  dec_w3^T (o>=165 zero-padded)
#define OFF_WAPE  218112   // [2][64][32][4] enc_res_wa packed
#define OFF_WBTE  234496   // [2][32][256]   enc_res_wb^T
#define OFF_WAPD  250880   // [2][64][32][4] dec_res_wa packed
#define OFF_WBTD  267264   // [2][32][256]   dec_res_wb^T
#define OFF_ETG   283648   // [4][512][64]  codebook row-major
#define OFF_EN2   414720   // [4][512]      ||e_k||^2
#define OFF_DSUM  416768   // [1]
#define PREP_N    416769

// ---------------- fused prep kernel: all weight transposes + codebook tables ----
__global__ void prep_k(const float* __restrict__ ew1, const float* __restrict__ ew2,
                       const float* __restrict__ ew3, const float* __restrict__ qw,
                       const float* __restrict__ dw1, const float* __restrict__ dw2,
                       const float* __restrict__ dw3, const float* __restrict__ ewa,
                       const float* __restrict__ ewb, const float* __restrict__ dwa,
                       const float* __restrict__ dwb, const float* __restrict__ embeds,
                       float* __restrict__ W) {
  int idx = blockIdx.x * 256 + threadIdx.x;
  if (idx < 21504) {  // wT1 [168][128] <- ew1 [128][165]
    int k = idx >> 7, o = idx & 127;
    W[OFF_WT1 + idx] = (k < 165) ? ew1[o * 165 + k] : 0.f;
    return;
  }
  idx -= 21504;
  if (idx < 32768) {  // wT2 [128][256] <- ew2 [256][128]
    int k = idx >> 8, o = idx & 255;
    W[OFF_WT2 + idx] = ew2[o * 128 + k];
    return;
  }
  idx -= 32768;
  if (idx < 65536) {  // wT3 [256][256] <- ew3 [256][256]
    int k = idx >> 8, o = idx & 255;
    W[OFF_WT3 + idx] = ew3[o * 256 + k];
    return;
  }
  idx -= 65536;
  if (idx < 16384) {  // wTq [256][64] <- qw [64][256]
    int k = idx >> 6, o = idx & 63;
    W[OFF_WTQ + idx] = qw[o * 256 + k];
    return;
  }
  idx -= 16384;
  if (idx < 16384) {  // wTd1 [64][256] <- dw1 [256][64]
    int k = idx >> 8, o = idx & 255;
    W[OFF_WTD1 + idx] = dw1[o * 64 + k];
    return;
  }
  idx -= 16384;
  if (idx < 32768) {  // wTd2 [256][128] <- dw2 [128][256]
    int k = idx >> 7, o = idx & 127;
    W[OFF_WTD2 + idx] = dw2[o * 256 + k];
    return;
  }
  idx -= 32768;
  if (idx < 32768) {  // wTd3 [128][256] <- dw3 [165][128], pad o>=165
    int k = idx >> 8, o = idx & 255;
    W[OFF_WTD3 + idx] = (o < 165) ? dw3[o * 128 + k] : 0.f;
    return;
  }
  idx -= 32768;
  if (idx < 16384) {  // waPe [2][64][32][4] <- ewa [2][32][256]
    int l = idx >> 13, rem = idx & 8191;
    int k4 = rem >> 7, rem2 = rem & 127, o = rem2 >> 2, kk = rem2 & 3;
    W[OFF_WAPE + idx] = ewa[l * 8192 + o * 256 + k4 * 4 + kk];
    return;
  }
  idx -= 16384;
  if (idx < 16384) {  // wbTe [2][32][256] <- ewb [2][256][32]
    int l = idx >> 13, rem = idx & 8191;
    int k = rem >> 8, o = rem & 255;
    W[OFF_WBTE + idx] = ewb[l * 8192 + o * 32 + k];
    return;
  }
  idx -= 16384;
  if (idx < 16384) {  // waPd
    int l = idx >> 13, rem = idx & 8191;
    int k4 = rem >> 7, rem2 = rem & 127, o = rem2 >> 2, kk = rem2 & 3;
    W[OFF_WAPD + idx] = dwa[l * 8192 + o * 256 + k4 * 4 + kk];
    return;
  }
  idx -= 16384;
  if (idx < 16384) {  // wbTd
    int l = idx >> 13, rem = idx & 8191;
    int k = rem >> 8, o = rem & 255;
    W[OFF_WBTD + idx] = dwb[l * 8192 + o * 32 + k];
    return;
  }
  idx -= 16384;
  if (idx < 131072) {  // etg[l][k][d] = embeds[l][d][k]
    int d = idx & 63, k = (idx >> 6) & 511, l = idx >> 15;
    W[OFF_ETG + idx] = embeds[(l * 64 + d) * 512 + k];
    return;
  }
  idx -= 131072;
  if (idx < 2048) {  // en2
    int l = idx >> 9, k = idx & 511;
    float s = 0.f;
    for (int d = 0; d < 64; ++d) {
      float e = embeds[(l * 64 + d) * 512 + k];
      s = fmaf(e, e, s);
    }
    W[OFF_EN2 + idx] = s;
    return;
  }
  idx -= 2048;
  if (idx == 0) W[OFF_DSUM] = 0.f;
}

// ---------------- 1x1-conv, transposed weights, coalesced everything ----------------
// 32 rows/block, 256 threads (4 waves, 8 rows/wave). Lane owns CP consecutive
// outputs o = lane*CP+j; weight loads wT[k][lane*CP] are fully coalesced
// dwordx{CP}; x comes from LDS wave-uniform broadcast; stores are vector &
// coalesced. One barrier total. Safe in-place (reads precede writes per row).
template <int CIN, int CINP, int COUT, int CP, int INSTRIDE, int OUTSTRIDE, bool RELU_IN,
          bool RELU_OUT>
__global__ __launch_bounds__(256, 4) void conv2_k(const float* in, const float* __restrict__ wT,
                                                  const float* __restrict__ b, float* out) {
  constexpr int COUTP = 64 * CP;
  constexpr bool GUARD = (COUT != COUTP);
  typedef float vCP __attribute__((ext_vector_type(CP)));
  __shared__ float xs[32][CINP];
  const int tid = threadIdx.x, lane = tid & 63, wv = tid >> 6;
  const long row0 = (long)blockIdx.x * 32;

  for (int i = tid; i < 32 * CINP; i += 256) {
    const int r = i / CINP, c = i % CINP;
    float v = (CIN == CINP || c < CIN) ? in[(row0 + r) * (long)INSTRIDE + c] : 0.f;
    if (RELU_IN) v = frelu(v);
    xs[r][c] = v;
  }
  __syncthreads();

  float acc[8][CP];
#pragma unroll
  for (int i = 0; i < 8; ++i)
#pragma unroll
    for (int j = 0; j < CP; ++j) acc[i][j] = 0.f;

  const float* wbase = wT + lane * CP;
#pragma unroll 4
  for (int k0 = 0; k0 < CINP; k0 += 4) {
    vCP wk[4];
#pragma unroll
    for (int kk = 0; kk < 4; ++kk) wk[kk] = *(const vCP*)(wbase + (k0 + kk) * COUTP);
#pragma unroll
    for (int rj = 0; rj < 8; ++rj) {
      const float4 x = *(const float4*)(&xs[wv * 8 + rj][k0]);
#pragma unroll
      for (int j = 0; j < CP; ++j) {
        acc[rj][j] = fmaf(x.x, wk[0][j], acc[rj][j]);
        acc[rj][j] = fmaf(x.y, wk[1][j], acc[rj][j]);
        acc[rj][j] = fmaf(x.z, wk[2][j], acc[rj][j]);
        acc[rj][j] = fmaf(x.w, wk[3][j], acc[rj][j]);
      }
    }
  }

  float bias[CP];
#pragma unroll
  for (int j = 0; j < CP; ++j) {
    const int o = lane * CP + j;
    bias[j] = (!GUARD || o < COUT) ? b[o] : 0.f;
  }
#pragma unroll
  for (int rj = 0; rj < 8; ++rj) {
    const long rbase = (row0 + wv * 8 + rj) * (long)OUTSTRIDE;
    if constexpr (!GUARD) {
      vCP v;
#pragma unroll
      for (int j = 0; j < CP; ++j) {
        const float t = acc[rj][j] + bias[j];
        v[j] = RELU_OUT ? frelu(t) : t;
      }
      *(vCP*)(out + rbase + lane * CP) = v;
    } else {
#pragma unroll
      for (int j = 0; j < CP; ++j) {
        const int o = lane * CP + j;
        if (o < COUT) {
          const float t = acc[rj][j] + bias[j];
          out[rbase + o] = RELU_OUT ? frelu(t) : t;
        }
      }
    }
  }
}

// ---------------- fused ResBlock PAIR, weights staged in LDS ----------------
// 64 rows/block, 512 threads (8 waves, 8 rows/wave), IN-PLACE on xbuf.
// R4/R5 read wa/wb from global PER WAVE: 128 KB x 4 waves x 2048 blocks
// = 1.07 GB, which matched FETCH_SIZE exactly (all missing L2). Now each
// 32 KB weight matrix is staged ONCE per block into one reused LDS buffer:
// {bar, stage wa, bar, phaseA, bar, stage wb, bar, phaseB} x 2 levels.
// Rows are wave-private: phase A reads x from global (half-wave broadcast,
// L1/L2-hot), phase B reads residual + writes x' in place — the level0->
// level1 round trip needs no extra barriers (same-wave vmcnt ordering).
__global__ __launch_bounds__(512, 4) void resblock_pair_k(
    float* xbuf, const float* __restrict__ waP, const float* __restrict__ ba,
    const float* __restrict__ wbT, const float* __restrict__ bb) {
  __shared__ float wls[8192];   // 32 KB, holds wa(li) then wb(li)
  __shared__ float ts[64][36];  // 9 KB, wave-private rows
  const int tid = threadIdx.x, lane = tid & 63, wv = tid >> 6;
  const long row0 = (long)blockIdx.x * 64;
  const int o32 = lane & 31, rh = lane >> 5;

  for (int li = 0; li < 2; ++li) {
    // ---- stage wa(li): packed [64][32][4], waP[k4][o][kk] = wa[o][k4*4+kk] ----
    __syncthreads();  // previous phase-B wls readers done
    for (int i = tid; i < 8192; i += 512) wls[i] = waP[li * 8192 + i];
    __syncthreads();

    // ---- phase A: t[r][o32] = relu(wa . relu(x[r]) + ba), 4 rows per half-wave ----
    {
      float a0 = 0.f, a1 = 0.f, a2 = 0.f, a3 = 0.f;
      const float* xrow = xbuf + (row0 + wv * 8 + rh * 4) * (long)SB;
#pragma unroll 4
      for (int k0 = 0; k0 < 256; k0 += 4) {
        const float4 wq = *(const float4*)(&wls[k0 * 32 + o32 * 4]);
        const float4 x0 = *(const float4*)(xrow + 0 * SB + k0);
        const float4 x1 = *(const float4*)(xrow + 1 * SB + k0);
        const float4 x2 = *(const float4*)(xrow + 2 * SB + k0);
        const float4 x3 = *(const float4*)(xrow + 3 * SB + k0);
        a0 = fmaf(frelu(x0.x), wq.x, a0);
        a0 = fmaf(frelu(x0.y), wq.y, a0);
        a0 = fmaf(frelu(x0.z), wq.z, a0);
        a0 = fmaf(frelu(x0.w), wq.w, a0);
        a1 = fmaf(frelu(x1.x), wq.x, a1);
        a1 = fmaf(frelu(x1.y), wq.y, a1);
        a1 = fmaf(frelu(x1.z), wq.z, a1);
        a1 = fmaf(frelu(x1.w), wq.w, a1);
        a2 = fmaf(frelu(x2.x), wq.x, a2);
        a2 = fmaf(frelu(x2.y), wq.y, a2);
        a2 = fmaf(frelu(x2.z), wq.z, a2);
        a2 = fmaf(frelu(x2.w), wq.w, a2);
        a3 = fmaf(frelu(x3.x), wq.x, a3);
        a3 = fmaf(frelu(x3.y), wq.y, a3);
        a3 = fmaf(frelu(x3.z), wq.z, a3);
        a3 = fmaf(frelu(x3.w), wq.w, a3);
      }
      const float bal = ba[li * 32 + o32];
      const int rB = wv * 8 + rh * 4;
      ts[rB + 0][o32] = frelu(a0 + bal);
      ts[rB + 1][o32] = frelu(a1 + bal);
      ts[rB + 2][o32] = frelu(a2 + bal);
      ts[rB + 3][o32] = frelu(a3 + bal);
    }

    // ---- stage wb(li): wbT[k][o] ----
    __syncthreads();  // all phase-A wls reads done
    for (int i = tid; i < 8192; i += 512) wls[i] = wbT[li * 8192 + i];
    __syncthreads();

    // ---- phase B: x[r] += wb . t[r] + bb (wave-local rows; ts by same wave) ----
    float acc2[8][4];
#pragma unroll
    for (int i = 0; i < 8; ++i)
#pragma unroll
      for (int j = 0; j < 4; ++j) acc2[i][j] = 0.f;

#pragma unroll
    for (int k0 = 0; k0 < 32; k0 += 4) {
      const float4 wk0 = *(const float4*)(&wls[(k0 + 0) * 256 + lane * 4]);
      const float4 wk1 = *(const float4*)(&wls[(k0 + 1) * 256 + lane * 4]);
      const float4 wk2 = *(const float4*)(&wls[(k0 + 2) * 256 + lane * 4]);
      const float4 wk3 = *(const float4*)(&wls[(k0 + 3) * 256 + lane * 4]);
#pragma unroll
      for (int rj = 0; rj < 8; ++rj) {
        const float4 t4 = *(const float4*)(&ts[wv * 8 + rj][k0]);
        acc2[rj][0] = fmaf(t4.x, wk0.x, acc2[rj][0]);
        acc2[rj][1] = fmaf(t4.x, wk0.y, acc2[rj][1]);
        acc2[rj][2] = fmaf(t4.x, wk0.z, acc2[rj][2]);
        acc2[rj][3] = fmaf(t4.x, wk0.w, acc2[rj][3]);
        acc2[rj][0] = fmaf(t4.y, wk1.x, acc2[rj][0]);
        acc2[rj][1] = fmaf(t4.y, wk1.y, acc2[rj][1]);
        acc2[rj][2] = fmaf(t4.y, wk1.z, acc2[rj][2]);
        acc2[rj][3] = fmaf(t4.y, wk1.w, acc2[rj][3]);
        acc2[rj][0] = fmaf(t4.z, wk2.x, acc2[rj][0]);
        acc2[rj][1] = fmaf(t4.z, wk2.y, acc2[rj][1]);
        acc2[rj][2] = fmaf(t4.z, wk2.z, acc2[rj][2]);
        acc2[rj][3] = fmaf(t4.z, wk2.w, acc2[rj][3]);
        acc2[rj][0] = fmaf(t4.w, wk3.x, acc2[rj][0]);
        acc2[rj][1] = fmaf(t4.w, wk3.y, acc2[rj][1]);
        acc2[rj][2] = fmaf(t4.w, wk3.z, acc2[rj][2]);
        acc2[rj][3] = fmaf(t4.w, wk3.w, acc2[rj][3]);
      }
    }
    const float4 bbv = *(const float4*)(bb + li * 256 + lane * 4);
#pragma unroll
    for (int rj = 0; rj < 8; ++rj) {
      float* xp = xbuf + (row0 + wv * 8 + rj) * (long)SB + lane * 4;
      const float4 xv = *(const float4*)xp;
      float4 nv;
      nv.x = xv.x + acc2[rj][0] + bbv.x;
      nv.y = xv.y + acc2[rj][1] + bbv.y;
      nv.z = xv.z + acc2[rj][2] + bbv.z;
      nv.w = xv.w + acc2[rj][3] + bbv.w;
      *(float4*)xp = nv;
    }
  }
}

// ---------------- residual VQ (4 levels, exact fp32 argmin) ----------------
// Barrier-free, coalesced codebook reads from global ([l][d][k] layout,
// lane-consecutive float4, L2-resident). score = en2[k] - 2*res.e_k.
// First-min tie-break identical to jnp.argmin.
__global__ __launch_bounds__(256, 4) void vq_k(float* buf, const float* __restrict__ embeds,
                                               const float* __restrict__ en2,
                                               const float* __restrict__ etg,
                                               float* __restrict__ dsum) {
  __shared__ float resL[32][68];
  const int tid = threadIdx.x;
  const int lane = tid & 63;
  const int wv = tid >> 6;
  const long row0 = (long)blockIdx.x * 32;

  for (int rj = 0; rj < 8; ++rj) {
    const int r = wv * 8 + rj;
    resL[r][lane] = buf[(row0 + r) * (long)SB + lane];
  }

  float dloc = 0.f;

  for (int l = 0; l < 4; ++l) {
    float best[8];
    int bk[8];
#pragma unroll
    for (int i = 0; i < 8; ++i) {
      best[i] = 3.4e38f;
      bk[i] = 0;
    }

    for (int kc = 0; kc < 2; ++kc) {
      float acc[8][4];
#pragma unroll
      for (int i = 0; i < 8; ++i)
#pragma unroll
        for (int j = 0; j < 4; ++j) acc[i][j] = 0.f;

      const float* eb = embeds + ((long)l << 15) + (kc << 8) + lane * 4;
#pragma unroll 2
      for (int dq = 0; dq < 16; ++dq) {
        float4 x4[8];
#pragma unroll
        for (int rj = 0; rj < 8; ++rj) x4[rj] = *(const float4*)(&resL[wv * 8 + rj][dq * 4]);
#pragma unroll
        for (int dd = 0; dd < 4; ++dd) {
          const float4 e4 = *(const float4*)(eb + ((dq * 4 + dd) << 9));
#pragma unroll
          for (int rj = 0; rj < 8; ++rj) {
            const float xv = dd == 0 ? x4[rj].x : dd == 1 ? x4[rj].y : dd == 2 ? x4[rj].z : x4[rj].w;
            acc[rj][0] = fmaf(xv, e4.x, acc[rj][0]);
            acc[rj][1] = fmaf(xv, e4.y, acc[rj][1]);
            acc[rj][2] = fmaf(xv, e4.z, acc[rj][2]);
            acc[rj][3] = fmaf(xv, e4.w, acc[rj][3]);
          }
        }
      }

      const float4 e2 = *(const float4*)(en2 + l * 512 + kc * 256 + lane * 4);
#pragma unroll
      for (int rj = 0; rj < 8; ++rj) {
#pragma unroll
        for (int j = 0; j < 4; ++j) {
          const float ev = j == 0 ? e2.x : j == 1 ? e2.y : j == 2 ? e2.z : e2.w;
          const float s = fmaf(-2.f, acc[rj][j], ev);
          const int k = kc * 256 + lane * 4 + j;
          if (s < best[rj]) {
            best[rj] = s;
            bk[rj] = k;
          }
        }
      }
    }

    // cross-lane first-min argmin
#pragma unroll
    for (int rj = 0; rj < 8; ++rj) {
      float bv = best[rj];
      int bi = bk[rj];
#pragma unroll
      for (int m = 1; m < 64; m <<= 1) {
        const float ov = __shfl_xor(bv, m, 64);
        const int ok = __shfl_xor(bi, m, 64);
        if (ov < bv || (ov == bv && ok < bi)) {
          bv = ov;
          bi = ok;
        }
      }
      bk[rj] = bi;
    }

    // gather + straight-through update
#pragma unroll
    for (int rj = 0; rj < 8; ++rj) {
      const int r = wv * 8 + rj;
      const float q = etg[((long)((l << 9) + bk[rj])) * 64 + lane];
      const float res = resL[r][lane];
      const float t = q - res;
      const float qst = res + t;
      dloc = fmaf(t, t, dloc);
      resL[r][lane] = res - qst;
      if (l == 0) buf[(row0 + r) * (long)SB + lane] = qst;
    }
  }

#pragma unroll
  for (int m = 1; m < 64; m <<= 1) dloc += __shfl_xor(dloc, m, 64);
  if (lane == 0) atomicAdd(dsum, dloc);
}

__global__ void finalize_k(const float* __restrict__ dsum, float* __restrict__ out) {
  if (threadIdx.x == 0 && blockIdx.x == 0)
    out[0] = *dsum * (1.0f / (4.0f * 65536.0f * 64.0f));
}

// ---------------- launch ----------------
extern "C" void kernel_launch(void* const* d_in, const int* in_sizes, int n_in, void* d_out,
                              int out_size, void* d_ws, size_t ws_size, hipStream_t stream) {
  (void)in_sizes; (void)n_in; (void)out_size; (void)ws_size;
  const float* x = (const float*)d_in[0];
  const float* enc_w1 = (const float*)d_in[1];
  const float* enc_b1 = (const float*)d_in[2];
  const float* enc_w2 = (const float*)d_in[3];
  const float* enc_b2 = (const float*)d_in[4];
  const float* enc_w3 = (const float*)d_in[5];
  const float* enc_b3 = (const float*)d_in[6];
  const float* enc_res_wa = (const float*)d_in[7];
  const float* enc_res_ba = (const float*)d_in[8];
  const float* enc_res_wb = (const float*)d_in[9];
  const float* enc_res_bb = (const float*)d_in[10];
  const float* q_w = (const float*)d_in[11];
  const float* q_b = (const float*)d_in[12];
  const float* embeds = (const float*)d_in[13];
  const float* dec_w1 = (const float*)d_in[14];
  const float* dec_b1 = (const float*)d_in[15];
  const float* dec_res_wa = (const float*)d_in[16];
  const float* dec_res_ba = (const float*)d_in[17];
  const float* dec_res_wb = (const float*)d_in[18];
  const float* dec_res_bb = (const float*)d_in[19];
  const float* dec_w2 = (const float*)d_in[20];
  const float* dec_b2 = (const float*)d_in[21];
  const float* dec_w3 = (const float*)d_in[22];
  const float* dec_b3 = (const float*)d_in[23];

  float* ws = (float*)d_ws;
  float* buf = ws;                          // [N][256]
  float* W = ws + (long)NROWS * SB;         // weight/codebook region

  float* dout = (float*)d_out;

  prep_k<<<(PREP_N + 255) / 256, 256, 0, stream>>>(enc_w1, enc_w2, enc_w3, q_w, dec_w1, dec_w2,
                                                   dec_w3, enc_res_wa, enc_res_wb, dec_res_wa,
                                                   dec_res_wb, embeds, W);

  const int GB = NROWS / 32;   // 2048 blocks (convs, vq)
  const int GR = NROWS / 64;   // 1024 blocks (resblock pairs)

  // encoder
  conv2_k<165, 168, 128, 2, 165, SB, false, true><<<GB, 256, 0, stream>>>(x, W + OFF_WT1, enc_b1, buf);
  conv2_k<128, 128, 256, 4, SB, SB, false, true><<<GB, 256, 0, stream>>>(buf, W + OFF_WT2, enc_b2, buf);
  conv2_k<256, 256, 256, 4, SB, SB, false, false><<<GB, 256, 0, stream>>>(buf, W + OFF_WT3, enc_b3, buf);
  resblock_pair_k<<<GR, 512, 0, stream>>>(buf, W + OFF_WAPE, enc_res_ba, W + OFF_WBTE, enc_res_bb);
  conv2_k<256, 256, 64, 1, SB, SB, true, false><<<GB, 256, 0, stream>>>(buf, W + OFF_WTQ, q_b, buf);

  // residual VQ
  vq_k<<<GB, 256, 0, stream>>>(buf, embeds, W + OFF_EN2, W + OFF_ETG, W + OFF_DSUM);

  // decoder
  conv2_k<64, 64, 256, 4, SB, SB, false, false><<<GB, 256, 0, stream>>>(buf, W + OFF_WTD1, dec_b1, buf);
  resblock_pair_k<<<GR, 512, 0, stream>>>(buf, W + OFF_WAPD, dec_res_ba, W + OFF_WBTD, dec_res_bb);
  conv2_k<256, 256, 128, 2, SB, SB, true, true><<<GB, 256, 0, stream>>>(buf, W + OFF_WTD2, dec_b2, buf);
  conv2_k<128, 128, 165, 4, SB, 165, false, false><<<GB, 256, 0, stream>>>(buf, W + OFF_WTD3, dec_b3, dout);

  finalize_k<<<1, 64, 0, stream>>>(W + OFF_DSUM, dout + (long)NROWS * 165);
}